// Round 13
// baseline (4821.028 us; speedup 1.0000x reference)
//
#include <hip/hip_runtime.h>
#include <hip/hip_fp16.h>
#include <math.h>

#define B_ 64
#define T_ 512

typedef _Float16 h2_t __attribute__((ext_vector_type(2)));

__device__ __forceinline__ float fdot2u(unsigned int a, unsigned int b, float c) {
#if __has_builtin(__builtin_amdgcn_fdot2)
    return __builtin_amdgcn_fdot2(__builtin_bit_cast(h2_t, a),
                                  __builtin_bit_cast(h2_t, b), c, false);
#else
    const __half2 ah = __builtin_bit_cast(__half2, a);
    const __half2 bh = __builtin_bit_cast(__half2, b);
    const float2 af = __half22float2(ah), bf = __half22float2(bh);
    return c + af.x * bf.x + af.y * bf.y;
#endif
}
__device__ __forceinline__ unsigned int pack_h2(float x, float y) {
    const __half2 h = __float22half2_rn(make_float2(x, y));
    return __builtin_bit_cast(unsigned int, h);
}
__device__ __forceinline__ unsigned short f2h_bits(float x) {
    return __builtin_bit_cast(unsigned short, (_Float16)x);
}

__device__ __forceinline__ float fsig(float z) { return 1.f / (1.f + __expf(-z)); }
__device__ __forceinline__ float ftanh(float z) {
    const float e = __expf(2.f * z);
    return 1.f - 2.f / (e + 1.f);
}

// ---------------------------------------------------------------------------
// GEMM: C[M,N] = (A[M,K]*mask)@W[K,N] + bias, packed-fp16 dot2 (r10, verified)
// ---------------------------------------------------------------------------
__global__ __launch_bounds__(256) void gemm_mask_f16(
    const float* __restrict__ A, const float* __restrict__ W,
    const float* __restrict__ bias, const float* __restrict__ mask,
    float* __restrict__ C, int M, int N, int K)
{
    const int TM = 64, TN = 64, TK = 32, KP = 16;
    __shared__ __align__(16) unsigned int As2[KP][68];
    __shared__ __align__(16) unsigned int Bs2[KP][68];

    const int tid = threadIdx.x;
    const int bn = blockIdx.x;
    const int bm = blockIdx.y;
    const int row0 = bm * TM;
    const int b = row0 / T_;

    const int ty = tid >> 4;
    const int tx = tid & 15;
    const int m0 = ty * 4;
    const int n0 = tx * 4;

    float acc[4][4];
#pragma unroll
    for (int i = 0; i < 4; i++)
#pragma unroll
        for (int j = 0; j < 4; j++) acc[i][j] = 0.f;

    for (int kk = 0; kk < K; kk += TK) {
        {
            const int m = tid >> 2;
            const int kq = (tid & 3) * 8;
            const float4 mv0 = *(const float4*)(mask + (size_t)b * K + kk + kq);
            const float4 mv1 = *(const float4*)(mask + (size_t)b * K + kk + kq + 4);
            const float4 a0 = *(const float4*)(A + (size_t)(row0 + m) * K + kk + kq);
            const float4 a1 = *(const float4*)(A + (size_t)(row0 + m) * K + kk + kq + 4);
            As2[kq / 2 + 0][m] = pack_h2(a0.x * mv0.x, a0.y * mv0.y);
            As2[kq / 2 + 1][m] = pack_h2(a0.z * mv0.z, a0.w * mv0.w);
            As2[kq / 2 + 2][m] = pack_h2(a1.x * mv1.x, a1.y * mv1.y);
            As2[kq / 2 + 3][m] = pack_h2(a1.z * mv1.z, a1.w * mv1.w);
        }
        {
            const int kp = tid >> 4;
            const int nq = (tid & 15) * 4;
            const float4 w0 = *(const float4*)(W + (size_t)(kk + 2 * kp) * N + bn * TN + nq);
            const float4 w1 = *(const float4*)(W + (size_t)(kk + 2 * kp + 1) * N + bn * TN + nq);
            uint4 pv;
            pv.x = pack_h2(w0.x, w1.x);
            pv.y = pack_h2(w0.y, w1.y);
            pv.z = pack_h2(w0.z, w1.z);
            pv.w = pack_h2(w0.w, w1.w);
            *(uint4*)&Bs2[kp][nq] = pv;
        }
        __syncthreads();

#pragma unroll
        for (int kp = 0; kp < KP; kp++) {
            const uint4 a4 = *(const uint4*)&As2[kp][m0];
            const uint4 b4 = *(const uint4*)&Bs2[kp][n0];
            acc[0][0] = fdot2u(a4.x, b4.x, acc[0][0]); acc[0][1] = fdot2u(a4.x, b4.y, acc[0][1]);
            acc[0][2] = fdot2u(a4.x, b4.z, acc[0][2]); acc[0][3] = fdot2u(a4.x, b4.w, acc[0][3]);
            acc[1][0] = fdot2u(a4.y, b4.x, acc[1][0]); acc[1][1] = fdot2u(a4.y, b4.y, acc[1][1]);
            acc[1][2] = fdot2u(a4.y, b4.z, acc[1][2]); acc[1][3] = fdot2u(a4.y, b4.w, acc[1][3]);
            acc[2][0] = fdot2u(a4.z, b4.x, acc[2][0]); acc[2][1] = fdot2u(a4.z, b4.y, acc[2][1]);
            acc[2][2] = fdot2u(a4.z, b4.z, acc[2][2]); acc[2][3] = fdot2u(a4.z, b4.w, acc[2][3]);
            acc[3][0] = fdot2u(a4.w, b4.x, acc[3][0]); acc[3][1] = fdot2u(a4.w, b4.y, acc[3][1]);
            acc[3][2] = fdot2u(a4.w, b4.z, acc[3][2]); acc[3][3] = fdot2u(a4.w, b4.w, acc[3][3]);
        }
        __syncthreads();
    }

    const float4 bv = *(const float4*)(bias + bn * TN + n0);
#pragma unroll
    for (int i = 0; i < 4; i++) {
        float4 v;
        v.x = acc[i][0] + bv.x;
        v.y = acc[i][1] + bv.y;
        v.z = acc[i][2] + bv.z;
        v.w = acc[i][3] + bv.w;
        *(float4*)&C[(size_t)(row0 + m0 + i) * N + bn * TN + n0] = v;
    }
}

// ---------------------------------------------------------------------------
// LSTM recurrence v13: back to 256 blocks (v10 grid), overhead deleted.
//  - Unit-major U in LDS: UW2[w][4*j+g]; thread (kq,j) owns the 4 gate
//    columns of hidden unit j -> uint4 LDS reads at 16B stride (0 conflicts
//    in r12 profile). After the zpart reduce the reducer thread holds all 4
//    gate pre-activations of its unit: act+cell+h computed IN-THREAD.
//    act_sh, the cell wave, and one barrier are gone.
//  - Pull-your-own-h: every thread spin-loads only its k-range's tagged
//    words (contiguous 64B, wave-uniform address) straight into registers.
//    No hW in LDS, no pull-share wave, no third barrier.
//  - 2 barriers/step: bar1 (zpart RAW), bar2 (zpart WAR, placed right after
//    the reducer's zpart reads so non-reducers release early).
//  - Tagged-word protocol unchanged (r10/r12-verified): word={tag,fp16 h},
//    parity double-buffer, skew bounded by the pull-before-advance induction.
// ---------------------------------------------------------------------------
template <int HN>
__global__ __launch_bounds__(1024) void lstm_rec_v13(
    const float* __restrict__ xz,       // [B, T, 4*HN]
    const float* __restrict__ U,        // [HN, 4*HN]
    float* __restrict__ hout,           // [B, T, HN] or nullptr
    float* __restrict__ out_last,       // [B, HN] or nullptr
    unsigned int* __restrict__ hbuf)    // [2][B_*HN] tagged words
{
    constexpr int GATES = 4 * HN;
    constexpr int HB = HN / 4;            // hidden units per block (64 / 32)
    constexpr int NKG = 1024 / HB;        // k-groups (16 / 32)
    constexpr int KWORDS = HN / 2;        // half2 words over k (128 / 64)
    constexpr int WPT = KWORDS / NKG;     // k-words per thread (8 / 2)

    __shared__ __align__(16) unsigned int UW2[KWORDS * HN];  // [w][4*j+g]
    __shared__ __align__(16) float4 zpart[NKG * HB];

    const int tid = threadIdx.x;
    const int q = blockIdx.x >> 6;        // quarter 0..3
    const int b = blockIdx.x & 63;        // batch element (siblings share XCD)

    const int j = tid % HB;               // local hidden unit
    const int kq = tid / HB;              // k-group
    const int wbase = kq * WPT;
    const int u0 = 2 * wbase;             // first global h-unit this thread needs
    const bool red = (kq == NKG - 1);     // reducer role
    const int gu = q * HB + j;            // global unit owned (reducer)

    // ---- one-time: stage U into LDS, unit-major [w][4*j+g] ----
    {
        constexpr int NP = 1024 / HN;
        const int c = tid % HN;           // 4*j + g
        const int part = tid / HN;
        const int uj = c >> 2, g = c & 3;
        const int gcol = g * HN + q * HB + uj;
        for (int w = part; w < KWORDS; w += NP)
            UW2[w * HN + c] = pack_h2(U[(size_t)(2 * w) * GATES + gcol],
                                      U[(size_t)(2 * w + 1) * GATES + gcol]);
    }

    unsigned int hreg[WPT];
#pragma unroll
    for (int i = 0; i < WPT; ++i) hreg[i] = 0u;   // h_0 = 0

    float cst = 0.f;
    float4 z0 = make_float4(0.f, 0.f, 0.f, 0.f);
    if (red) {
        const float* xzt = xz + (size_t)b * T_ * GATES;
        z0.x = xzt[0 * HN + gu];
        z0.y = xzt[1 * HN + gu];
        z0.z = xzt[2 * HN + gu];
        z0.w = xzt[3 * HN + gu];
    }
    __syncthreads();

#pragma unroll 1
    for (int t = 0; t < T_; ++t) {
        // ---- dot: 4 gate partials of unit j over this thread's k-words ----
        float4 acc = make_float4(0.f, 0.f, 0.f, 0.f);
#pragma unroll
        for (int i = 0; i < WPT; ++i) {
            const uint4 uv = *(const uint4*)&UW2[(wbase + i) * HN + 4 * j];
            acc.x = fdot2u(uv.x, hreg[i], acc.x);   // gate i
            acc.y = fdot2u(uv.y, hreg[i], acc.y);   // gate f
            acc.z = fdot2u(uv.z, hreg[i], acc.z);   // gate g
            acc.w = fdot2u(uv.w, hreg[i], acc.w);   // gate o
        }
        zpart[kq * HB + j] = acc;
        __syncthreads();                            // bar1 (zpart RAW)

        float4 z;
        if (red) {
            z = z0;
#pragma unroll
            for (int r = 0; r < NKG; ++r) {
                const float4 p = zpart[r * HB + j];
                z.x += p.x; z.y += p.y; z.z += p.z; z.w += p.w;
            }
        }
        __syncthreads();                            // bar2 (zpart WAR; early release)

        if (red) {
            const float ig = fsig(z.x);
            const float fg = fsig(z.y);
            const float gg = ftanh(z.z);
            const float og = fsig(z.w);
            cst = fg * cst + ig * gg;
            const float hnew = og * ftanh(cst);
            if (t < T_ - 1) {
                unsigned int* hslot = hbuf + (size_t)(t & 1) * B_ * HN + (size_t)b * HN;
                const unsigned int word =
                    ((unsigned int)(t + 1) << 16) | (unsigned int)f2h_bits(hnew);
                __hip_atomic_store(&hslot[gu], word,
                                   __ATOMIC_RELAXED, __HIP_MEMORY_SCOPE_AGENT);
            }
            if (hout) hout[((size_t)b * T_ + t) * HN + gu] = hnew;
            if (out_last && t == T_ - 1) out_last[(size_t)b * HN + gu] = hnew;
            if (t + 1 < T_) {                       // prefetch next xz
                const float* xzt = xz + ((size_t)b * T_ + (t + 1)) * GATES;
                z0.x = xzt[0 * HN + gu];
                z0.y = xzt[1 * HN + gu];
                z0.z = xzt[2 * HN + gu];
                z0.w = xzt[3 * HN + gu];
            }
        }

        // ---- pull h(t): each thread loads ONLY its k-range (wave-uniform) ----
        if (t < T_ - 1) {
            const unsigned long long* hq = (const unsigned long long*)
                (hbuf + (size_t)(t & 1) * B_ * HN + (size_t)b * HN + u0);
            const unsigned long long tg = (unsigned long long)(t + 1);
            unsigned long long v[WPT];
#pragma unroll
            for (int i = 0; i < WPT; ++i)
                v[i] = __hip_atomic_load(&hq[i], __ATOMIC_RELAXED, __HIP_MEMORY_SCOPE_AGENT);
#pragma unroll
            for (int i = 0; i < WPT; ++i) {
                while ((((v[i] >> 16) & 0xffffull) != tg) || ((v[i] >> 48) != tg))
                    v[i] = __hip_atomic_load(&hq[i], __ATOMIC_RELAXED, __HIP_MEMORY_SCOPE_AGENT);
                hreg[i] = (unsigned int)(v[i] & 0xffffu) |
                          ((unsigned int)((v[i] >> 32) & 0xffffu) << 16);
            }
        }
    }
}

// ---------------------------------------------------------------------------
// Launch
// ---------------------------------------------------------------------------
extern "C" void kernel_launch(void* const* d_in, const int* in_sizes, int n_in,
                              void* d_out, int out_size, void* d_ws, size_t ws_size,
                              hipStream_t stream)
{
    const float* x  = (const float*)d_in[0];
    const float* W0 = (const float*)d_in[1];
    const float* U0 = (const float*)d_in[2];
    const float* b0 = (const float*)d_in[3];
    const float* W1 = (const float*)d_in[4];
    const float* U1 = (const float*)d_in[5];
    const float* b1 = (const float*)d_in[6];
    const float* W2 = (const float*)d_in[7];
    const float* U2 = (const float*)d_in[8];
    const float* b2 = (const float*)d_in[9];
    const float* m0 = (const float*)d_in[10];
    const float* m1 = (const float*)d_in[11];
    const float* m2 = (const float*)d_in[12];
    float* out = (float*)d_out;

    // workspace layout:
    //   xz    : 134217728 B
    //   h0    :  33554432 B
    //   h1    :  33554432 B
    //   hbuf  : 3 regions x 131072 B (2 x 64 x 256 tagged words per layer)
    char* ws = (char*)d_ws;
    float* xz = (float*)ws;
    float* h0 = (float*)(ws + 134217728);
    float* h1 = (float*)(ws + 134217728 + 33554432);
    unsigned int* hb0 = (unsigned int*)(ws + 134217728 + 2 * 33554432);
    unsigned int* hb1 = hb0 + 2 * B_ * 256;
    unsigned int* hb2 = hb1 + 2 * B_ * 256;

    const int M = B_ * T_;  // 32768

    // Layer 0
    gemm_mask_f16<<<dim3(1024 / 64, M / 64), 256, 0, stream>>>(x, W0, b0, m0, xz, M, 1024, 128);
    lstm_rec_v13<256><<<256, 1024, 0, stream>>>(xz, U0, h0, nullptr, hb0);

    // Layer 1
    gemm_mask_f16<<<dim3(1024 / 64, M / 64), 256, 0, stream>>>(h0, W1, b1, m1, xz, M, 1024, 256);
    lstm_rec_v13<256><<<256, 1024, 0, stream>>>(xz, U1, h1, nullptr, hb1);

    // Layer 2 (H=128), emit last h only
    gemm_mask_f16<<<dim3(512 / 64, M / 64), 256, 0, stream>>>(h1, W2, b2, m2, xz, M, 512, 256);
    lstm_rec_v13<128><<<256, 1024, 0, stream>>>(xz, U2, nullptr, out, hb2);
}

// Round 14
// 3335.737 us; speedup vs baseline: 1.4453x; 1.4453x over previous
//
#include <hip/hip_runtime.h>
#include <hip/hip_fp16.h>
#include <math.h>

#define B_ 64
#define T_ 512

typedef _Float16 h2_t __attribute__((ext_vector_type(2)));

__device__ __forceinline__ float fdot2u(unsigned int a, unsigned int b, float c) {
#if __has_builtin(__builtin_amdgcn_fdot2)
    return __builtin_amdgcn_fdot2(__builtin_bit_cast(h2_t, a),
                                  __builtin_bit_cast(h2_t, b), c, false);
#else
    const __half2 ah = __builtin_bit_cast(__half2, a);
    const __half2 bh = __builtin_bit_cast(__half2, b);
    const float2 af = __half22float2(ah), bf = __half22float2(bh);
    return c + af.x * bf.x + af.y * bf.y;
#endif
}
__device__ __forceinline__ unsigned int pack_h2(float x, float y) {
    const __half2 h = __float22half2_rn(make_float2(x, y));
    return __builtin_bit_cast(unsigned int, h);
}
__device__ __forceinline__ unsigned short f2h_bits(float x) {
    return __builtin_bit_cast(unsigned short, (_Float16)x);
}

__device__ __forceinline__ float fsig(float z) { return 1.f / (1.f + __expf(-z)); }
__device__ __forceinline__ float ftanh(float z) {
    const float e = __expf(2.f * z);
    return 1.f - 2.f / (e + 1.f);
}

// ---------------------------------------------------------------------------
// GEMM: C[M,N] = (A[M,K]*mask)@W[K,N] + bias, packed-fp16 dot2 (r10, verified)
// ---------------------------------------------------------------------------
__global__ __launch_bounds__(256) void gemm_mask_f16(
    const float* __restrict__ A, const float* __restrict__ W,
    const float* __restrict__ bias, const float* __restrict__ mask,
    float* __restrict__ C, int M, int N, int K)
{
    const int TM = 64, TN = 64, TK = 32, KP = 16;
    __shared__ __align__(16) unsigned int As2[KP][68];
    __shared__ __align__(16) unsigned int Bs2[KP][68];

    const int tid = threadIdx.x;
    const int bn = blockIdx.x;
    const int bm = blockIdx.y;
    const int row0 = bm * TM;
    const int b = row0 / T_;

    const int ty = tid >> 4;
    const int tx = tid & 15;
    const int m0 = ty * 4;
    const int n0 = tx * 4;

    float acc[4][4];
#pragma unroll
    for (int i = 0; i < 4; i++)
#pragma unroll
        for (int j = 0; j < 4; j++) acc[i][j] = 0.f;

    for (int kk = 0; kk < K; kk += TK) {
        {
            const int m = tid >> 2;
            const int kq = (tid & 3) * 8;
            const float4 mv0 = *(const float4*)(mask + (size_t)b * K + kk + kq);
            const float4 mv1 = *(const float4*)(mask + (size_t)b * K + kk + kq + 4);
            const float4 a0 = *(const float4*)(A + (size_t)(row0 + m) * K + kk + kq);
            const float4 a1 = *(const float4*)(A + (size_t)(row0 + m) * K + kk + kq + 4);
            As2[kq / 2 + 0][m] = pack_h2(a0.x * mv0.x, a0.y * mv0.y);
            As2[kq / 2 + 1][m] = pack_h2(a0.z * mv0.z, a0.w * mv0.w);
            As2[kq / 2 + 2][m] = pack_h2(a1.x * mv1.x, a1.y * mv1.y);
            As2[kq / 2 + 3][m] = pack_h2(a1.z * mv1.z, a1.w * mv1.w);
        }
        {
            const int kp = tid >> 4;
            const int nq = (tid & 15) * 4;
            const float4 w0 = *(const float4*)(W + (size_t)(kk + 2 * kp) * N + bn * TN + nq);
            const float4 w1 = *(const float4*)(W + (size_t)(kk + 2 * kp + 1) * N + bn * TN + nq);
            uint4 pv;
            pv.x = pack_h2(w0.x, w1.x);
            pv.y = pack_h2(w0.y, w1.y);
            pv.z = pack_h2(w0.z, w1.z);
            pv.w = pack_h2(w0.w, w1.w);
            *(uint4*)&Bs2[kp][nq] = pv;
        }
        __syncthreads();

#pragma unroll
        for (int kp = 0; kp < KP; kp++) {
            const uint4 a4 = *(const uint4*)&As2[kp][m0];
            const uint4 b4 = *(const uint4*)&Bs2[kp][n0];
            acc[0][0] = fdot2u(a4.x, b4.x, acc[0][0]); acc[0][1] = fdot2u(a4.x, b4.y, acc[0][1]);
            acc[0][2] = fdot2u(a4.x, b4.z, acc[0][2]); acc[0][3] = fdot2u(a4.x, b4.w, acc[0][3]);
            acc[1][0] = fdot2u(a4.y, b4.x, acc[1][0]); acc[1][1] = fdot2u(a4.y, b4.y, acc[1][1]);
            acc[1][2] = fdot2u(a4.y, b4.z, acc[1][2]); acc[1][3] = fdot2u(a4.y, b4.w, acc[1][3]);
            acc[2][0] = fdot2u(a4.z, b4.x, acc[2][0]); acc[2][1] = fdot2u(a4.z, b4.y, acc[2][1]);
            acc[2][2] = fdot2u(a4.z, b4.z, acc[2][2]); acc[2][3] = fdot2u(a4.z, b4.w, acc[2][3]);
            acc[3][0] = fdot2u(a4.w, b4.x, acc[3][0]); acc[3][1] = fdot2u(a4.w, b4.y, acc[3][1]);
            acc[3][2] = fdot2u(a4.w, b4.z, acc[3][2]); acc[3][3] = fdot2u(a4.w, b4.w, acc[3][3]);
        }
        __syncthreads();
    }

    const float4 bv = *(const float4*)(bias + bn * TN + n0);
#pragma unroll
    for (int i = 0; i < 4; i++) {
        float4 v;
        v.x = acc[i][0] + bv.x;
        v.y = acc[i][1] + bv.y;
        v.z = acc[i][2] + bv.z;
        v.w = acc[i][3] + bv.w;
        *(float4*)&C[(size_t)(row0 + m0 + i) * N + bn * TN + n0] = v;
    }
}

// ---------------------------------------------------------------------------
// LSTM recurrence v14 = v10's pull pattern + v13's unit-major cell + wave
// role concurrency.
// r13 lesson: agent-scope atomic loads with SAME address across 64 lanes
// serialize at the coherence point (no broadcast coalescing) -> never spin
// wave-uniform. v14 pulls with one wave, DISTINCT per-lane qwords (the v10
// pattern measured at 985 us), sharing via LDS hW.
// Layout: unit-major UW2[w][4*j+g]; thread (kq,j) dots the 4 gates of unit j
// (uint4 reads, 0 conflicts in r12/r13 profiles). Wave NKG-1 = reducer:
// reduce zpart -> act+cell IN-THREAD -> publish tagged words (coalesced) ->
// xz prefetch. Wave 0 = puller: concurrently spin-pulls h(t) into hW; its
// L3 round-trips overlap the reducer's compute. 2 barriers/step.
// Tagged-word protocol (r10-verified): word={tag(hi16), fp16 h(lo16)},
// parity double-buffer, skew bounded by pull-before-advance induction.
// ---------------------------------------------------------------------------
template <int HN>
__global__ __launch_bounds__(1024) void lstm_rec_v14(
    const float* __restrict__ xz,       // [B, T, 4*HN]
    const float* __restrict__ U,        // [HN, 4*HN]
    float* __restrict__ hout,           // [B, T, HN] or nullptr
    float* __restrict__ out_last,       // [B, HN] or nullptr
    unsigned int* __restrict__ hbuf)    // [2][B_*HN] tagged words
{
    constexpr int GATES = 4 * HN;
    constexpr int HB = HN / 4;            // hidden units per block (64 / 32)
    constexpr int NKG = 1024 / HB;        // k-groups (16 / 32)
    constexpr int KWORDS = HN / 2;        // half2 words over k (128 / 64)
    constexpr int WPT = KWORDS / NKG;     // k-words per thread (8 / 2)

    __shared__ __align__(16) unsigned int UW2[KWORDS * HN];  // [w][4*j+g]
    __shared__ __align__(16) unsigned int hW[KWORDS];
    __shared__ __align__(16) float4 zpart[NKG * HB];

    const int tid = threadIdx.x;
    const int q = blockIdx.x >> 6;        // quarter 0..3
    const int b = blockIdx.x & 63;        // batch element (siblings share XCD)

    const int j = tid % HB;               // local hidden unit
    const int kq = tid / HB;              // k-group
    const int wbase = kq * WPT;
    const bool red = (kq == NKG - 1);     // reducer role (top wave)
    const bool puller = (tid < 64);       // wave 0
    const int gu = q * HB + j;            // global unit (reducer's unit)

    // ---- one-time: stage U into LDS, unit-major [w][4*j+g] ----
    {
        constexpr int NP = 1024 / HN;
        const int c = tid % HN;           // 4*j + g
        const int part = tid / HN;
        const int uj = c >> 2, g = c & 3;
        const int gcol = g * HN + q * HB + uj;
        for (int w = part; w < KWORDS; w += NP)
            UW2[w * HN + c] = pack_h2(U[(size_t)(2 * w) * GATES + gcol],
                                      U[(size_t)(2 * w + 1) * GATES + gcol]);
    }
    if (tid < KWORDS) hW[tid] = 0u;       // h_0 = 0

    float cst = 0.f;
    float4 z0 = make_float4(0.f, 0.f, 0.f, 0.f);
    if (red) {
        const float* xzt = xz + (size_t)b * T_ * GATES;
        z0.x = xzt[0 * HN + gu];
        z0.y = xzt[1 * HN + gu];
        z0.z = xzt[2 * HN + gu];
        z0.w = xzt[3 * HN + gu];
    }
    __syncthreads();

#pragma unroll 1
    for (int t = 0; t < T_; ++t) {
        // ---- dot: 4 gate partials of unit j over this thread's k-words ----
        unsigned int hr[WPT];
#pragma unroll
        for (int i = 0; i < WPT; ++i) hr[i] = hW[wbase + i];   // bcast reads
        float4 acc = make_float4(0.f, 0.f, 0.f, 0.f);
#pragma unroll
        for (int i = 0; i < WPT; ++i) {
            const uint4 uv = *(const uint4*)&UW2[(wbase + i) * HN + 4 * j];
            acc.x = fdot2u(uv.x, hr[i], acc.x);   // gate i
            acc.y = fdot2u(uv.y, hr[i], acc.y);   // gate f
            acc.z = fdot2u(uv.z, hr[i], acc.z);   // gate g
            acc.w = fdot2u(uv.w, hr[i], acc.w);   // gate o
        }
        zpart[kq * HB + j] = acc;
        __syncthreads();                          // bar1 (zpart RAW, hW WAR)

        if (red) {
            // reduce + act + cell in-thread, then publish
            float4 z = z0;
#pragma unroll
            for (int r = 0; r < NKG; ++r) {
                const float4 p = zpart[r * HB + j];
                z.x += p.x; z.y += p.y; z.z += p.z; z.w += p.w;
            }
            const float ig = fsig(z.x);
            const float fg = fsig(z.y);
            const float gg = ftanh(z.z);
            const float og = fsig(z.w);
            cst = fg * cst + ig * gg;
            const float hnew = og * ftanh(cst);
            if (t < T_ - 1) {
                unsigned int* hslot = hbuf + (size_t)(t & 1) * B_ * HN + (size_t)b * HN;
                const unsigned int word =
                    ((unsigned int)(t + 1) << 16) | (unsigned int)f2h_bits(hnew);
                __hip_atomic_store(&hslot[gu], word,
                                   __ATOMIC_RELAXED, __HIP_MEMORY_SCOPE_AGENT);
            }
            if (hout) hout[((size_t)b * T_ + t) * HN + gu] = hnew;
            if (out_last && t == T_ - 1) out_last[(size_t)b * HN + gu] = hnew;
            if (t + 1 < T_) {                     // prefetch next xz
                const float* xzt = xz + ((size_t)b * T_ + (t + 1)) * GATES;
                z0.x = xzt[0 * HN + gu];
                z0.y = xzt[1 * HN + gu];
                z0.z = xzt[2 * HN + gu];
                z0.w = xzt[3 * HN + gu];
            }
        } else if (puller && t < T_ - 1) {
            // wave 0: spin-pull h(t) with DISTINCT per-lane qwords -> hW.
            // Overlaps the reducer wave's compute (different waves).
            const unsigned long long* hq = (const unsigned long long*)
                (hbuf + (size_t)(t & 1) * B_ * HN + (size_t)b * HN);
            const unsigned long long tg = (unsigned long long)(t + 1);
            if constexpr (HN == 256) {
                // 128 qwords: lane l -> qwords l and l+64 (fully coalesced)
                unsigned long long v0 = __hip_atomic_load(&hq[tid],
                    __ATOMIC_RELAXED, __HIP_MEMORY_SCOPE_AGENT);
                unsigned long long v1 = __hip_atomic_load(&hq[tid + 64],
                    __ATOMIC_RELAXED, __HIP_MEMORY_SCOPE_AGENT);
                while ((((v0 >> 16) & 0xffffull) != tg) || ((v0 >> 48) != tg))
                    v0 = __hip_atomic_load(&hq[tid],
                        __ATOMIC_RELAXED, __HIP_MEMORY_SCOPE_AGENT);
                while ((((v1 >> 16) & 0xffffull) != tg) || ((v1 >> 48) != tg))
                    v1 = __hip_atomic_load(&hq[tid + 64],
                        __ATOMIC_RELAXED, __HIP_MEMORY_SCOPE_AGENT);
                hW[tid] = (unsigned int)(v0 & 0xffffu) |
                          ((unsigned int)((v0 >> 32) & 0xffffu) << 16);
                hW[tid + 64] = (unsigned int)(v1 & 0xffffu) |
                               ((unsigned int)((v1 >> 32) & 0xffffu) << 16);
            } else {
                // 64 qwords: lane l -> qword l
                unsigned long long v0 = __hip_atomic_load(&hq[tid],
                    __ATOMIC_RELAXED, __HIP_MEMORY_SCOPE_AGENT);
                while ((((v0 >> 16) & 0xffffull) != tg) || ((v0 >> 48) != tg))
                    v0 = __hip_atomic_load(&hq[tid],
                        __ATOMIC_RELAXED, __HIP_MEMORY_SCOPE_AGENT);
                hW[tid] = (unsigned int)(v0 & 0xffffu) |
                          ((unsigned int)((v0 >> 32) & 0xffffu) << 16);
            }
        }
        __syncthreads();                          // bar2 (zpart WAR, hW RAW)
    }
}

// ---------------------------------------------------------------------------
// Launch
// ---------------------------------------------------------------------------
extern "C" void kernel_launch(void* const* d_in, const int* in_sizes, int n_in,
                              void* d_out, int out_size, void* d_ws, size_t ws_size,
                              hipStream_t stream)
{
    const float* x  = (const float*)d_in[0];
    const float* W0 = (const float*)d_in[1];
    const float* U0 = (const float*)d_in[2];
    const float* b0 = (const float*)d_in[3];
    const float* W1 = (const float*)d_in[4];
    const float* U1 = (const float*)d_in[5];
    const float* b1 = (const float*)d_in[6];
    const float* W2 = (const float*)d_in[7];
    const float* U2 = (const float*)d_in[8];
    const float* b2 = (const float*)d_in[9];
    const float* m0 = (const float*)d_in[10];
    const float* m1 = (const float*)d_in[11];
    const float* m2 = (const float*)d_in[12];
    float* out = (float*)d_out;

    // workspace layout:
    //   xz    : 134217728 B
    //   h0    :  33554432 B
    //   h1    :  33554432 B
    //   hbuf  : 3 regions x 131072 B (2 x 64 x 256 tagged words per layer)
    char* ws = (char*)d_ws;
    float* xz = (float*)ws;
    float* h0 = (float*)(ws + 134217728);
    float* h1 = (float*)(ws + 134217728 + 33554432);
    unsigned int* hb0 = (unsigned int*)(ws + 134217728 + 2 * 33554432);
    unsigned int* hb1 = hb0 + 2 * B_ * 256;
    unsigned int* hb2 = hb1 + 2 * B_ * 256;

    const int M = B_ * T_;  // 32768

    // Layer 0
    gemm_mask_f16<<<dim3(1024 / 64, M / 64), 256, 0, stream>>>(x, W0, b0, m0, xz, M, 1024, 128);
    lstm_rec_v14<256><<<256, 1024, 0, stream>>>(xz, U0, h0, nullptr, hb0);

    // Layer 1
    gemm_mask_f16<<<dim3(1024 / 64, M / 64), 256, 0, stream>>>(h0, W1, b1, m1, xz, M, 1024, 256);
    lstm_rec_v14<256><<<256, 1024, 0, stream>>>(xz, U1, h1, nullptr, hb1);

    // Layer 2 (H=128), emit last h only
    gemm_mask_f16<<<dim3(512 / 64, M / 64), 256, 0, stream>>>(h1, W2, b2, m2, xz, M, 512, 256);
    lstm_rec_v14<128><<<256, 1024, 0, stream>>>(xz, U2, nullptr, out, hb2);
}

// Round 15
// 3113.448 us; speedup vs baseline: 1.5485x; 1.0714x over previous
//
#include <hip/hip_runtime.h>
#include <hip/hip_fp16.h>
#include <math.h>

#define B_ 64
#define T_ 512

typedef _Float16 h2_t __attribute__((ext_vector_type(2)));

__device__ __forceinline__ float fdot2u(unsigned int a, unsigned int b, float c) {
#if __has_builtin(__builtin_amdgcn_fdot2)
    return __builtin_amdgcn_fdot2(__builtin_bit_cast(h2_t, a),
                                  __builtin_bit_cast(h2_t, b), c, false);
#else
    const __half2 ah = __builtin_bit_cast(__half2, a);
    const __half2 bh = __builtin_bit_cast(__half2, b);
    const float2 af = __half22float2(ah), bf = __half22float2(bh);
    return c + af.x * bf.x + af.y * bf.y;
#endif
}
__device__ __forceinline__ unsigned int pack_h2(float x, float y) {
    const __half2 h = __float22half2_rn(make_float2(x, y));
    return __builtin_bit_cast(unsigned int, h);
}
__device__ __forceinline__ unsigned short f2h_bits(float x) {
    return __builtin_bit_cast(unsigned short, (_Float16)x);
}

__device__ __forceinline__ float fsig(float z) { return 1.f / (1.f + __expf(-z)); }
__device__ __forceinline__ float ftanh(float z) {
    const float e = __expf(2.f * z);
    return 1.f - 2.f / (e + 1.f);
}

// ---------------------------------------------------------------------------
// GEMM: C[M,N] = (A[M,K]*mask)@W[K,N] + bias, packed-fp16 dot2 (r10, verified)
// ---------------------------------------------------------------------------
__global__ __launch_bounds__(256) void gemm_mask_f16(
    const float* __restrict__ A, const float* __restrict__ W,
    const float* __restrict__ bias, const float* __restrict__ mask,
    float* __restrict__ C, int M, int N, int K)
{
    const int TM = 64, TN = 64, TK = 32, KP = 16;
    __shared__ __align__(16) unsigned int As2[KP][68];
    __shared__ __align__(16) unsigned int Bs2[KP][68];

    const int tid = threadIdx.x;
    const int bn = blockIdx.x;
    const int bm = blockIdx.y;
    const int row0 = bm * TM;
    const int b = row0 / T_;

    const int ty = tid >> 4;
    const int tx = tid & 15;
    const int m0 = ty * 4;
    const int n0 = tx * 4;

    float acc[4][4];
#pragma unroll
    for (int i = 0; i < 4; i++)
#pragma unroll
        for (int j = 0; j < 4; j++) acc[i][j] = 0.f;

    for (int kk = 0; kk < K; kk += TK) {
        {
            const int m = tid >> 2;
            const int kq = (tid & 3) * 8;
            const float4 mv0 = *(const float4*)(mask + (size_t)b * K + kk + kq);
            const float4 mv1 = *(const float4*)(mask + (size_t)b * K + kk + kq + 4);
            const float4 a0 = *(const float4*)(A + (size_t)(row0 + m) * K + kk + kq);
            const float4 a1 = *(const float4*)(A + (size_t)(row0 + m) * K + kk + kq + 4);
            As2[kq / 2 + 0][m] = pack_h2(a0.x * mv0.x, a0.y * mv0.y);
            As2[kq / 2 + 1][m] = pack_h2(a0.z * mv0.z, a0.w * mv0.w);
            As2[kq / 2 + 2][m] = pack_h2(a1.x * mv1.x, a1.y * mv1.y);
            As2[kq / 2 + 3][m] = pack_h2(a1.z * mv1.z, a1.w * mv1.w);
        }
        {
            const int kp = tid >> 4;
            const int nq = (tid & 15) * 4;
            const float4 w0 = *(const float4*)(W + (size_t)(kk + 2 * kp) * N + bn * TN + nq);
            const float4 w1 = *(const float4*)(W + (size_t)(kk + 2 * kp + 1) * N + bn * TN + nq);
            uint4 pv;
            pv.x = pack_h2(w0.x, w1.x);
            pv.y = pack_h2(w0.y, w1.y);
            pv.z = pack_h2(w0.z, w1.z);
            pv.w = pack_h2(w0.w, w1.w);
            *(uint4*)&Bs2[kp][nq] = pv;
        }
        __syncthreads();

#pragma unroll
        for (int kp = 0; kp < KP; kp++) {
            const uint4 a4 = *(const uint4*)&As2[kp][m0];
            const uint4 b4 = *(const uint4*)&Bs2[kp][n0];
            acc[0][0] = fdot2u(a4.x, b4.x, acc[0][0]); acc[0][1] = fdot2u(a4.x, b4.y, acc[0][1]);
            acc[0][2] = fdot2u(a4.x, b4.z, acc[0][2]); acc[0][3] = fdot2u(a4.x, b4.w, acc[0][3]);
            acc[1][0] = fdot2u(a4.y, b4.x, acc[1][0]); acc[1][1] = fdot2u(a4.y, b4.y, acc[1][1]);
            acc[1][2] = fdot2u(a4.y, b4.z, acc[1][2]); acc[1][3] = fdot2u(a4.y, b4.w, acc[1][3]);
            acc[2][0] = fdot2u(a4.z, b4.x, acc[2][0]); acc[2][1] = fdot2u(a4.z, b4.y, acc[2][1]);
            acc[2][2] = fdot2u(a4.z, b4.z, acc[2][2]); acc[2][3] = fdot2u(a4.z, b4.w, acc[2][3]);
            acc[3][0] = fdot2u(a4.w, b4.x, acc[3][0]); acc[3][1] = fdot2u(a4.w, b4.y, acc[3][1]);
            acc[3][2] = fdot2u(a4.w, b4.z, acc[3][2]); acc[3][3] = fdot2u(a4.w, b4.w, acc[3][3]);
        }
        __syncthreads();
    }

    const float4 bv = *(const float4*)(bias + bn * TN + n0);
#pragma unroll
    for (int i = 0; i < 4; i++) {
        float4 v;
        v.x = acc[i][0] + bv.x;
        v.y = acc[i][1] + bv.y;
        v.z = acc[i][2] + bv.z;
        v.w = acc[i][3] + bv.w;
        *(float4*)&C[(size_t)(row0 + m0 + i) * N + bn * TN + n0] = v;
    }
}

// ---------------------------------------------------------------------------
// LSTM recurrence v15: 8-way U split, 2 blocks/CU — the exchange RT is hidden
// by a CO-RESIDENT BLOCK's dot (true block-level latency hiding; r12 failed
// because both dots ran serially inside one block; r14 failed because no
// intra-block wave can outrun the slowest sibling's publish).
// 512-thread blocks; block (q,b) owns HB hidden units of batch b. Big layers:
// SPLIT=8 -> 64 KB U slice, 74 KB LDS/block, grid 512 = 2 blocks/CU.
// Layer 2: SPLIT=4 -> 32 KB slice, grid 256.
// Unit-major UW2[w][4*j+g] (uint4 dot reads, 0 conflicts r12-r14); hW reads
// vectorized to uint4 (was 8 scalar reads in v14). Reducer = top k-group
// (half of wave 7): reduce+act+cell in-thread, publish tagged words, xz
// prefetch. Puller = wave 0: distinct per-lane qword spins (v10 pattern).
// Tagged-word protocol unchanged: word={tag(hi16), fp16 h(lo16)}, parity
// double-buffer; skew bounded by pull-before-advance induction.
// ---------------------------------------------------------------------------
template <int HN, int SPLIT>
__global__ __launch_bounds__(512) void lstm_rec_v15(
    const float* __restrict__ xz,       // [B, T, 4*HN]
    const float* __restrict__ U,        // [HN, 4*HN]
    float* __restrict__ hout,           // [B, T, HN] or nullptr
    float* __restrict__ out_last,       // [B, HN] or nullptr
    unsigned int* __restrict__ hbuf)    // [2][B_*HN] tagged words
{
    constexpr int GATES = 4 * HN;
    constexpr int HB = HN / SPLIT;        // hidden units per block (32)
    constexpr int COLSB = 4 * HB;         // gate cols per block (128)
    constexpr int NKG = 512 / HB;         // k-groups (16)
    constexpr int KWORDS = HN / 2;        // half2 words over k (128 / 64)
    constexpr int WPT = KWORDS / NKG;     // k-words per thread (8 / 4)
    constexpr int QW = KWORDS / 2;        // qwords per batch h (128.. wait) 

    __shared__ __align__(16) unsigned int UW2[KWORDS * COLSB];  // [w][4*j+g]
    __shared__ __align__(16) unsigned int hW[KWORDS];
    __shared__ __align__(16) float4 zpart[NKG * HB];

    const int tid = threadIdx.x;
    const int q = blockIdx.x >> 6;        // slice 0..SPLIT-1
    const int b = blockIdx.x & 63;        // batch element (siblings share XCD)

    const int j = tid % HB;               // local hidden unit
    const int kq = tid / HB;              // k-group
    const int wbase = kq * WPT;
    const bool red = (kq == NKG - 1);     // reducer role
    const bool puller = (tid < 64);       // wave 0
    const int gu = q * HB + j;            // global unit owned (reducer)

    // ---- one-time: stage U slice into LDS, unit-major [w][4*j+g] ----
    {
        constexpr int NP = 512 / COLSB;   // 4
        const int c = tid % COLSB;        // 4*uj + g
        const int part = tid / COLSB;
        const int uj = c >> 2, g = c & 3;
        const int gcol = g * HN + q * HB + uj;
        for (int w = part; w < KWORDS; w += NP)
            UW2[w * COLSB + c] = pack_h2(U[(size_t)(2 * w) * GATES + gcol],
                                         U[(size_t)(2 * w + 1) * GATES + gcol]);
    }
    if (tid < KWORDS) hW[tid] = 0u;       // h_0 = 0

    float cst = 0.f;
    float4 z0 = make_float4(0.f, 0.f, 0.f, 0.f);
    if (red) {
        const float* xzt = xz + (size_t)b * T_ * GATES;
        z0.x = xzt[0 * HN + gu];
        z0.y = xzt[1 * HN + gu];
        z0.z = xzt[2 * HN + gu];
        z0.w = xzt[3 * HN + gu];
    }
    __syncthreads();

#pragma unroll 1
    for (int t = 0; t < T_; ++t) {
        // ---- dot: 4 gate partials of unit j over this thread's k-words ----
        unsigned int hr[WPT];
#pragma unroll
        for (int i4 = 0; i4 < WPT / 4; ++i4) {
            const uint4 h4 = *(const uint4*)&hW[wbase + 4 * i4];  // b128, bcast
            hr[4 * i4 + 0] = h4.x; hr[4 * i4 + 1] = h4.y;
            hr[4 * i4 + 2] = h4.z; hr[4 * i4 + 3] = h4.w;
        }
        float4 acc = make_float4(0.f, 0.f, 0.f, 0.f);
#pragma unroll
        for (int i = 0; i < WPT; ++i) {
            const uint4 uv = *(const uint4*)&UW2[(wbase + i) * COLSB + 4 * j];
            acc.x = fdot2u(uv.x, hr[i], acc.x);   // gate i
            acc.y = fdot2u(uv.y, hr[i], acc.y);   // gate f
            acc.z = fdot2u(uv.z, hr[i], acc.z);   // gate g
            acc.w = fdot2u(uv.w, hr[i], acc.w);   // gate o
        }
        zpart[tid] = acc;                          // tid == kq*HB + j
        __syncthreads();                           // bar1 (zpart RAW, hW WAR)

        if (red) {
            float4 z = z0;
#pragma unroll
            for (int r = 0; r < NKG; ++r) {
                const float4 p = zpart[r * HB + j];
                z.x += p.x; z.y += p.y; z.z += p.z; z.w += p.w;
            }
            const float ig = fsig(z.x);
            const float fg = fsig(z.y);
            const float gg = ftanh(z.z);
            const float og = fsig(z.w);
            cst = fg * cst + ig * gg;
            const float hnew = og * ftanh(cst);
            if (t < T_ - 1) {
                unsigned int* hslot = hbuf + (size_t)(t & 1) * B_ * HN + (size_t)b * HN;
                const unsigned int word =
                    ((unsigned int)(t + 1) << 16) | (unsigned int)f2h_bits(hnew);
                __hip_atomic_store(&hslot[gu], word,
                                   __ATOMIC_RELAXED, __HIP_MEMORY_SCOPE_AGENT);
            }
            if (hout) hout[((size_t)b * T_ + t) * HN + gu] = hnew;
            if (out_last && t == T_ - 1) out_last[(size_t)b * HN + gu] = hnew;
            if (t + 1 < T_) {                      // prefetch next xz
                const float* xzt = xz + ((size_t)b * T_ + (t + 1)) * GATES;
                z0.x = xzt[0 * HN + gu];
                z0.y = xzt[1 * HN + gu];
                z0.z = xzt[2 * HN + gu];
                z0.w = xzt[3 * HN + gu];
            }
        } else if (puller && t < T_ - 1) {
            // wave 0: spin-pull h(t), DISTINCT per-lane qwords -> hW
            const unsigned long long* hq = (const unsigned long long*)
                (hbuf + (size_t)(t & 1) * B_ * HN + (size_t)b * HN);
            const unsigned long long tg = (unsigned long long)(t + 1);
            if constexpr (HN == 256) {
                unsigned long long v0 = __hip_atomic_load(&hq[tid],
                    __ATOMIC_RELAXED, __HIP_MEMORY_SCOPE_AGENT);
                unsigned long long v1 = __hip_atomic_load(&hq[tid + 64],
                    __ATOMIC_RELAXED, __HIP_MEMORY_SCOPE_AGENT);
                while ((((v0 >> 16) & 0xffffull) != tg) || ((v0 >> 48) != tg))
                    v0 = __hip_atomic_load(&hq[tid],
                        __ATOMIC_RELAXED, __HIP_MEMORY_SCOPE_AGENT);
                while ((((v1 >> 16) & 0xffffull) != tg) || ((v1 >> 48) != tg))
                    v1 = __hip_atomic_load(&hq[tid + 64],
                        __ATOMIC_RELAXED, __HIP_MEMORY_SCOPE_AGENT);
                hW[tid] = (unsigned int)(v0 & 0xffffu) |
                          ((unsigned int)((v0 >> 32) & 0xffffu) << 16);
                hW[tid + 64] = (unsigned int)(v1 & 0xffffu) |
                               ((unsigned int)((v1 >> 32) & 0xffffu) << 16);
            } else {
                unsigned long long v0 = __hip_atomic_load(&hq[tid],
                    __ATOMIC_RELAXED, __HIP_MEMORY_SCOPE_AGENT);
                while ((((v0 >> 16) & 0xffffull) != tg) || ((v0 >> 48) != tg))
                    v0 = __hip_atomic_load(&hq[tid],
                        __ATOMIC_RELAXED, __HIP_MEMORY_SCOPE_AGENT);
                hW[tid] = (unsigned int)(v0 & 0xffffu) |
                          ((unsigned int)((v0 >> 32) & 0xffffu) << 16);
            }
        }
        __syncthreads();                           // bar2 (zpart WAR, hW RAW)
    }
    (void)QW;
}

// ---------------------------------------------------------------------------
// Launch
// ---------------------------------------------------------------------------
extern "C" void kernel_launch(void* const* d_in, const int* in_sizes, int n_in,
                              void* d_out, int out_size, void* d_ws, size_t ws_size,
                              hipStream_t stream)
{
    const float* x  = (const float*)d_in[0];
    const float* W0 = (const float*)d_in[1];
    const float* U0 = (const float*)d_in[2];
    const float* b0 = (const float*)d_in[3];
    const float* W1 = (const float*)d_in[4];
    const float* U1 = (const float*)d_in[5];
    const float* b1 = (const float*)d_in[6];
    const float* W2 = (const float*)d_in[7];
    const float* U2 = (const float*)d_in[8];
    const float* b2 = (const float*)d_in[9];
    const float* m0 = (const float*)d_in[10];
    const float* m1 = (const float*)d_in[11];
    const float* m2 = (const float*)d_in[12];
    float* out = (float*)d_out;

    // workspace layout:
    //   xz    : 134217728 B
    //   h0    :  33554432 B
    //   h1    :  33554432 B
    //   hbuf  : 3 regions x 131072 B (2 x 64 x 256 tagged words per layer)
    char* ws = (char*)d_ws;
    float* xz = (float*)ws;
    float* h0 = (float*)(ws + 134217728);
    float* h1 = (float*)(ws + 134217728 + 33554432);
    unsigned int* hb0 = (unsigned int*)(ws + 134217728 + 2 * 33554432);
    unsigned int* hb1 = hb0 + 2 * B_ * 256;
    unsigned int* hb2 = hb1 + 2 * B_ * 256;

    const int M = B_ * T_;  // 32768

    // Layer 0
    gemm_mask_f16<<<dim3(1024 / 64, M / 64), 256, 0, stream>>>(x, W0, b0, m0, xz, M, 1024, 128);
    lstm_rec_v15<256, 8><<<512, 512, 0, stream>>>(xz, U0, h0, nullptr, hb0);

    // Layer 1
    gemm_mask_f16<<<dim3(1024 / 64, M / 64), 256, 0, stream>>>(h0, W1, b1, m1, xz, M, 1024, 256);
    lstm_rec_v15<256, 8><<<512, 512, 0, stream>>>(xz, U1, h1, nullptr, hb1);

    // Layer 2 (H=128), emit last h only
    gemm_mask_f16<<<dim3(512 / 64, M / 64), 256, 0, stream>>>(h1, W2, b2, m2, xz, M, 512, 256);
    lstm_rec_v15<128, 4><<<256, 512, 0, stream>>>(xz, U2, nullptr, out, hb2);
}